// Round 8
// baseline (117.878 us; speedup 1.0000x reference)
//
#include <hip/hip_runtime.h>
#include <math.h>

// StructureLoss — R8: tall persistent bands to cut halo re-fetch.
// R7 post-mortem (WIN 122.7->106.5, main ~29 us): explicit load batching is
// the effective lever; occupancy is not. Remaining gap vs ~17 us floor is
// halo re-fetch (RG=16 -> t requested 3.9x, FETCH 106 MB).
// R8: 1 block/CU (256 blocks = 32 imgs x 8 bands of 64 rows); running sum
// carried across 4 sub-chunks of 16 rows -> halo factor 1.47. Next chunk's
// 32 row-loads issued before the barrier so stage-2 covers their latency;
// x/t prefetched per chunk (R7). launch_bounds(256,1) = free VGPR budget.
// Edge bands: clamp+mask loads, same pipeline (no straggler blocks).

#define IMG_H 512
#define IMG_W 512
#define NB    32
#define HW    (IMG_H * IMG_W)
#define BAND  64              // output rows per block
#define CH    16              // rows per sub-chunk
#define NCH   4               // sub-chunks per band
#define NBAND 8               // bands per image
#define NTH   256
#define VST   576             // LDS row stride; 512 + 16*4 skew

// skew +4 floats per 32-col chunk: chunk s occupies [36s, 36s+31], 16B-aligned
__device__ __forceinline__ int vidx(int c) { return c + 4 * (c >> 5); }

__device__ __forceinline__ float wave_reduce(float v) {
#pragma unroll
  for (int off = 32; off > 0; off >>= 1) v += __shfl_down(v, off, 64);
  return v;
}

template <bool EDGE>
__device__ __forceinline__ void do_band(const float* __restrict__ xb,
                                        const float* __restrict__ tb,
                                        const int r0, const int tid,
                                        float* __restrict__ vls,
                                        float& aW, float& aWB,
                                        float& aI, float& aU) {
  const float2* tc2 = (const float2*)tb + tid;   // row stride = 256 float2
  const int li  = vidx(2 * tid);
  const int row = tid >> 4;                      // stage-2: 0..15
  const int sub = tid & 15;                      // stage-2: 16-col... 32-col chunk
  const int c0  = sub * 32;

  // ---- warm-up: rows r0-15 .. r0+14 (3x10 batches, independent partials) ----
  float sx, sy;
  {
    float2 w[30];
    float  m[30];
#pragma unroll
    for (int j = 0; j < 30; ++j) {
      int r = r0 - 15 + j;
      if (EDGE) {
        int rc = r < 0 ? 0 : (r > 511 ? 511 : r);
        m[j] = (r == rc) ? 1.f : 0.f;
        w[j] = tc2[rc * 256];
      } else {
        w[j] = tc2[r * 256];
      }
    }
    float p0x = 0.f, p0y = 0.f, p1x = 0.f, p1y = 0.f, p2x = 0.f, p2y = 0.f;
#pragma unroll
    for (int j = 0; j < 10; ++j) {
      float mm = EDGE ? m[j] : 1.f;
      p0x = fmaf(mm, w[j].x, p0x); p0y = fmaf(mm, w[j].y, p0y);
    }
#pragma unroll
    for (int j = 10; j < 20; ++j) {
      float mm = EDGE ? m[j] : 1.f;
      p1x = fmaf(mm, w[j].x, p1x); p1y = fmaf(mm, w[j].y, p1y);
    }
#pragma unroll
    for (int j = 20; j < 30; ++j) {
      float mm = EDGE ? m[j] : 1.f;
      p2x = fmaf(mm, w[j].x, p2x); p2y = fmaf(mm, w[j].y, p2y);
    }
    sx = p0x + p1x + p2x; sy = p0y + p1y + p2y;
  }

  // ---- preload chunk-0 head/tail rows ----
  float2 h[CH], l[CH];
  float  mh[CH], ml[CH];
#pragma unroll
  for (int j = 0; j < CH; ++j) {
    int rh = r0 + j + 15;        // head rows r0+15 .. r0+30
    int rl = r0 + j - 15;        // tail rows r0-15 .. r0
    if (EDGE) {
      int rhc = rh > 511 ? 511 : rh;
      int rlc = rl < 0 ? 0 : rl;
      mh[j] = (rh == rhc) ? 1.f : 0.f;
      ml[j] = (rl == rlc) ? 1.f : 0.f;
      h[j] = tc2[rhc * 256];
      l[j] = tc2[rlc * 256];
    } else {
      h[j] = tc2[rh * 256];
      l[j] = tc2[rl * 256];
    }
  }

  const float inv_area = 1.0f / 961.0f;

#pragma unroll
  for (int k = 0; k < NCH; ++k) {
    // ---- stage 1: consume h/l, write 16 V rows to LDS ----
#pragma unroll
    for (int j = 0; j < CH; ++j) {
      float mhj = EDGE ? mh[j] : 1.f, mlj = EDGE ? ml[j] : 1.f;
      sx = fmaf(mhj, h[j].x, sx); sy = fmaf(mhj, h[j].y, sy);
      vls[j * VST + li] = sx; vls[j * VST + li + 1] = sy;
      sx = fmaf(-mlj, l[j].x, sx); sy = fmaf(-mlj, l[j].y, sy);
    }

    // ---- prefetch this chunk's x/t for stage 2 (consumed after scan) ----
    const float* xr = xb + (size_t)(r0 + k * CH + row) * IMG_W + c0;
    const float* tr = tb + (size_t)(r0 + k * CH + row) * IMG_W + c0;
    float4 xg[8], tg[8];
#pragma unroll
    for (int jc = 0; jc < 8; ++jc) {
      xg[jc] = *(const float4*)(xr + 4 * jc);
      tg[jc] = *(const float4*)(tr + 4 * jc);
    }

    // ---- prefetch next chunk's head/tail rows (covered by stage 2) ----
    float2 h2[CH], l2[CH];
    float  mh2[CH], ml2[CH];
    if (k < NCH - 1) {
#pragma unroll
      for (int j = 0; j < CH; ++j) {
        int rh = r0 + (k + 1) * CH + j + 15;
        int rl = r0 + (k + 1) * CH + j - 15;
        if (EDGE) {
          int rhc = rh > 511 ? 511 : rh;
          int rlc = rl < 0 ? 0 : rl;
          mh2[j] = (rh == rhc) ? 1.f : 0.f;
          ml2[j] = (rl == rlc) ? 1.f : 0.f;
          h2[j] = tc2[rhc * 256];
          l2[j] = tc2[rlc * 256];
        } else {
          h2[j] = tc2[rh * 256];
          l2[j] = tc2[rl * 256];
        }
      }
    }

    __syncthreads();

    // ---- stage 2: prefix sums + box + fused elementwise (R4-verified) ----
    {
      const float* vr = &vls[row * VST];
      float q[32];
      {
        const float4* rb4 = (const float4*)(vr + 36 * sub);
        float run = 0.f;
#pragma unroll
        for (int kk = 0; kk < 8; ++kk) {
          float4 vv = rb4[kk];
          q[4 * kk + 0] = run + vv.x;
          q[4 * kk + 1] = q[4 * kk + 0] + vv.y;
          q[4 * kk + 2] = q[4 * kk + 1] + vv.z;
          q[4 * kk + 3] = q[4 * kk + 2] + vv.w;
          run = q[4 * kk + 3];
        }
      }
      {
        float tot = q[31];
        float s = tot;
#pragma unroll
        for (int d = 1; d < 16; d <<= 1) {
          float u = __shfl_up(s, d, 64);
          if (sub >= d) s += u;
        }
        float base = s - tot;
#pragma unroll
        for (int j2 = 0; j2 < 32; ++j2) q[j2] += base;   // q[j]=P[c0+j]
      }
#pragma unroll
      for (int jc = 0; jc < 8; ++jc) {
        float xa[4] = {xg[jc].x, xg[jc].y, xg[jc].z, xg[jc].w};
        float ta[4] = {tg[jc].x, tg[jc].y, tg[jc].z, tg[jc].w};
#pragma unroll
        for (int e = 0; e < 4; ++e) {
          const int j2 = 4 * jc + e;
          float hi, lo;
          if (j2 <= 16) {
            hi = q[j2 + 15];
          } else {
            float g = __shfl_down(q[j2 - 17], 1);
            hi = (sub == 15) ? q[31] : g;
          }
          if (j2 >= 16) {
            lo = q[j2 - 16];
          } else {
            float g = __shfl_up(q[j2 + 16], 1);
            lo = (sub == 0) ? 0.f : g;
          }
          float box = hi - lo;
          float tv = ta[e], xv = xa[e];
          float w   = fmaf(5.0f, fabsf(box * inv_area - tv), 1.0f);
          float ez  = __expf(-fabsf(xv));            // single exp
          float inv = 1.0f / (1.0f + ez);
          float p   = (xv >= 0.f) ? inv : ez * inv;  // sigmoid(x)
          float bce = fmaxf(xv, 0.f) - xv * tv + __logf(1.0f + ez);
          aW  += w;
          aWB = fmaf(w, bce, aWB);
          aI  = fmaf(p * tv, w, aI);
          aU  = fmaf(p + tv, w, aU);
        }
      }
    }

    __syncthreads();   // protect LDS before next chunk's V writes

    if (k < NCH - 1) {
#pragma unroll
      for (int j = 0; j < CH; ++j) {
        h[j] = h2[j]; l[j] = l2[j];
        if (EDGE) { mh[j] = mh2[j]; ml[j] = ml2[j]; }
      }
    }
  }
}

__global__ __launch_bounds__(NTH, 1) void sloss_main(const float* __restrict__ x,
                                                     const float* __restrict__ t,
                                                     float* __restrict__ part) {
  __shared__ float vls[CH * VST];   // 16*576*4 = 36864 B
  __shared__ float red[4][4];

  const int tid  = threadIdx.x;
  // img = blockIdx&31: all 8 bands of an image land on one XCD (256 blocks
  // round-robin over 8 XCDs; 32 === 0 mod 8) -> band-boundary halos L2-hit.
  const int img  = blockIdx.x & 31;
  const int band = blockIdx.x >> 5;
  const int r0   = band * BAND;
  const float* tb = t + (size_t)img * HW;
  const float* xb = x + (size_t)img * HW;

  float aW = 0.f, aWB = 0.f, aI = 0.f, aU = 0.f;
  if (band == 0 || band == NBAND - 1)
    do_band<true>(xb, tb, r0, tid, vls, aW, aWB, aI, aU);
  else
    do_band<false>(xb, tb, r0, tid, vls, aW, aWB, aI, aU);

  aW  = wave_reduce(aW);
  aWB = wave_reduce(aWB);
  aI  = wave_reduce(aI);
  aU  = wave_reduce(aU);
  const int wv = tid >> 6, ln = tid & 63;
  if (ln == 0) { red[wv][0] = aW; red[wv][1] = aWB; red[wv][2] = aI; red[wv][3] = aU; }
  __syncthreads();
  if (tid < 4)
    part[(img * NBAND + band) * 4 + tid] =
        red[0][tid] + red[1][tid] + red[2][tid] + red[3][tid];
}

// ---- finalize: reduce 256 block-partials -> scalar loss ----
__global__ void sloss_final(const float* __restrict__ part,
                            float* __restrict__ out) {
  __shared__ float s[128];
  int tid = threadIdx.x;          // 128 threads
  int img = tid >> 2, q = tid & 3;
  float v = 0.f;
#pragma unroll
  for (int g = 0; g < NBAND; ++g) v += part[((img << 3) + g) * 4 + q];
  s[tid] = v;
  __syncthreads();
  float loss = 0.f;
  if (tid < NB) {
    float aW  = s[tid * 4 + 0];
    float aWB = s[tid * 4 + 1];
    float aI  = s[tid * 4 + 2];
    float aU  = s[tid * 4 + 3];
    loss = aWB / aW + 1.0f - (aI + 1.0f) / (aU - aI + 1.0f);
  }
  loss = wave_reduce(loss);
  if (tid == 0) out[0] = loss * (1.0f / (float)NB);
}

extern "C" void kernel_launch(void* const* d_in, const int* in_sizes, int n_in,
                              void* d_out, int out_size, void* d_ws, size_t ws_size,
                              hipStream_t stream) {
  const float* x = (const float*)d_in[0];
  const float* t = (const float*)d_in[1];
  float* part = (float*)d_ws;     // 256 x 4 floats, fully overwritten

  sloss_main<<<NB * NBAND, NTH, 0, stream>>>(x, t, part);
  sloss_final<<<1, 128, 0, stream>>>(part, (float*)d_out);
}

// Round 10
// 115.792 us; speedup vs baseline: 1.0180x; 1.0180x over previous
//
#include <hip/hip_runtime.h>
#include <math.h>

// StructureLoss — R9b: R7 structure + tail rows from registers (compile fix:
// nontemporal load via clang native vector type, not HIP_vector_type).
// R8 post-mortem: tall bands cut FETCH 106->48 MB but 1 block/CU (4 waves)
// regressed main 29->44 us -> concurrency dominates; kernel is request-path
// bound at ~6.8 TB/s with 16 waves/CU (R7), NOT HBM-bound.
// R9 keeps R7's winning shape (RG=16, 1024 blocks = 4/CU, 16 waves/CU, deep
// load batches) and removes redundant requests: the 16 tail rows are a
// subset of the 30 warm-up rows -> keep w[0..15] live in registers instead
// of re-loading (saves 33.5 MB of requests); x loads are nontemporal so the
// once-streamed x doesn't evict t's halo from L2.

#define IMG_H 512
#define IMG_W 512
#define NB    32
#define HW    (IMG_H * IMG_W)
#define RG    16              // output rows per block
#define NGRP  (IMG_H / RG)    // 32 row-groups per image
#define NTH   256
#define VST   576             // LDS row stride (floats); 512 + 16*4 skew

typedef float f4v __attribute__((ext_vector_type(4)));  // native vec for builtins

// skew +4 floats per 32-col chunk: chunk s occupies [36s, 36s+31], 16B-aligned
__device__ __forceinline__ int vidx(int c) { return c + 4 * (c >> 5); }

__device__ __forceinline__ float wave_reduce(float v) {
#pragma unroll
  for (int off = 32; off > 0; off >>= 1) v += __shfl_down(v, off, 64);
  return v;
}

__global__ __launch_bounds__(NTH, 4) void sloss_main(const float* __restrict__ x,
                                                     const float* __restrict__ t,
                                                     float* __restrict__ part) {
  __shared__ float vls[RG * VST];   // 16*576*4 = 36864 B -> 4 blocks/CU
  __shared__ float red[4][4];

  const int tid = threadIdx.x;
  // XCD swizzle: one image's 32 groups stay on one XCD -> halo rows L2-hit.
  const int xcd = blockIdx.x & 7;
  const int k   = blockIdx.x >> 3;        // 0..127
  const int img = (xcd << 2) | (k >> 5);  // 4 images per XCD
  const int grp = k & 31;
  const int r0  = grp * RG;
  const float* tb = t + (size_t)img * HW;
  const float* xb = x + (size_t)img * HW;

  // ---- Stage 1: vertical 31-row running sums; thread owns cols 2t,2t+1 ----
  {
    const float2* tc2 = (const float2*)tb + tid;   // row stride = 256 float2
    const int li = vidx(2 * tid);
    float sx, sy;
    if (grp >= 1 && grp <= 30) {                   // interior: no row guards
      // warm-up rows r0-15..r0+14 as one 30-load batch; w[0..15] stay live
      // as the main loop's tail rows (rows r0-15..r0) -- no tail re-loads.
      float2 w[30];
#pragma unroll
      for (int j = 0; j < 30; ++j) w[j] = tc2[(r0 - 15 + j) * 256];
      float ax = 0.f, ay = 0.f, bx2 = 0.f, by2 = 0.f, cx = 0.f, cy = 0.f;
#pragma unroll
      for (int j = 0; j < 10; ++j) { ax += w[j].x; ay += w[j].y; }
#pragma unroll
      for (int j = 10; j < 20; ++j) { bx2 += w[j].x; by2 += w[j].y; }
#pragma unroll
      for (int j = 20; j < 30; ++j) { cx += w[j].x; cy += w[j].y; }
      sx = ax + bx2 + cx; sy = ay + by2 + cy;
      // main loop: 4 rows/step, 4 head loads batched; tails from w[]
#pragma unroll
      for (int c = 0; c < 4; ++c) {
        float2 hd[4];
#pragma unroll
        for (int j = 0; j < 4; ++j) hd[j] = tc2[(r0 + 4 * c + j + 15) * 256];
#pragma unroll
        for (int j = 0; j < 4; ++j) {
          const int i = 4 * c + j;
          sx += hd[j].x; sy += hd[j].y;
          vls[i * VST + li] = sx; vls[i * VST + li + 1] = sy;
          sx -= w[i].x; sy -= w[i].y;    // tail row r0-15+i, from registers
        }
      }
    } else {                                       // edge groups: guarded
      sx = 0.f; sy = 0.f;
#pragma unroll
      for (int kk = -15; kk < 15; ++kk) {
        int r = r0 + kk;
        if ((unsigned)r < IMG_H) { float2 v = tc2[r * 256]; sx += v.x; sy += v.y; }
      }
#pragma unroll
      for (int i = 0; i < RG; ++i) {
        int ra = r0 + i + 15;
        if (ra < IMG_H) { float2 v = tc2[ra * 256]; sx += v.x; sy += v.y; }
        vls[i * VST + li] = sx; vls[i * VST + li + 1] = sy;
        int rs = r0 + i - 15;
        if (rs >= 0) { float2 u = tc2[rs * 256]; sx -= u.x; sy -= u.y; }
      }
    }
  }

  // ---- hoist stage-2 x/t loads: overlap with barrier + prefix scan ----
  const int row = tid >> 4;                 // 0..15
  const int sub = tid & 15;                 // 0..15 (32-col chunk)
  const int c0  = sub * 32;
  const float* xr = xb + (size_t)(r0 + row) * IMG_W + c0;
  const float* tr = tb + (size_t)(r0 + row) * IMG_W + c0;
  f4v xg[8], tg[8];
#pragma unroll
  for (int jc = 0; jc < 8; ++jc) {
    xg[jc] = __builtin_nontemporal_load((const f4v*)(xr + 4 * jc));
    tg[jc] = *(const f4v*)(tr + 4 * jc);
  }

  __syncthreads();

  // ---- Stage 2: row prefix sums + box from registers + fused elementwise ----
  const float* vr = &vls[row * VST];
  float q[32];
  {
    const float4* rb4 = (const float4*)(vr + 36 * sub);
    float run = 0.f;
#pragma unroll
    for (int kk = 0; kk < 8; ++kk) {
      float4 vv = rb4[kk];
      q[4 * kk + 0] = run + vv.x;
      q[4 * kk + 1] = q[4 * kk + 0] + vv.y;
      q[4 * kk + 2] = q[4 * kk + 1] + vv.z;
      q[4 * kk + 3] = q[4 * kk + 2] + vv.w;
      run = q[4 * kk + 3];
    }
  }
  // segmented (width-16) inclusive scan of chunk totals across the row
  {
    float tot = q[31];
    float s = tot;
#pragma unroll
    for (int d = 1; d < 16; d <<= 1) {
      float u = __shfl_up(s, d, 64);
      if (sub >= d) s += u;
    }
    float base = s - tot;
#pragma unroll
    for (int j = 0; j < 32; ++j) q[j] += base;   // q[j] = P[c0+j]
  }

  // box[c] = P[min(c+15,511)] - (c>=16 ? P[c-16] : 0); neighbors via shfl.
  const float inv_area = 1.0f / 961.0f;
  float aW = 0.f, aWB = 0.f, aI = 0.f, aU = 0.f;
#pragma unroll
  for (int jc = 0; jc < 8; ++jc) {
    float xa[4] = {xg[jc].x, xg[jc].y, xg[jc].z, xg[jc].w};
    float ta[4] = {tg[jc].x, tg[jc].y, tg[jc].z, tg[jc].w};
#pragma unroll
    for (int e = 0; e < 4; ++e) {
      const int j = 4 * jc + e;
      float hi, lo;
      if (j <= 16) {
        hi = q[j + 15];
      } else {
        float g = __shfl_down(q[j - 17], 1);
        hi = (sub == 15) ? q[31] : g;
      }
      if (j >= 16) {
        lo = q[j - 16];
      } else {
        float g = __shfl_up(q[j + 16], 1);
        lo = (sub == 0) ? 0.f : g;
      }
      float box = hi - lo;
      float tv = ta[e], xv = xa[e];
      float w   = fmaf(5.0f, fabsf(box * inv_area - tv), 1.0f);
      float ez  = __expf(-fabsf(xv));            // single exp
      float inv = 1.0f / (1.0f + ez);
      float p   = (xv >= 0.f) ? inv : ez * inv;  // sigmoid(x)
      float bce = fmaxf(xv, 0.f) - xv * tv + __logf(1.0f + ez);
      aW  += w;
      aWB = fmaf(w, bce, aWB);
      aI  = fmaf(p * tv, w, aI);
      aU  = fmaf(p + tv, w, aU);
    }
  }

  aW  = wave_reduce(aW);
  aWB = wave_reduce(aWB);
  aI  = wave_reduce(aI);
  aU  = wave_reduce(aU);
  const int wv = tid >> 6, ln = tid & 63;
  if (ln == 0) { red[wv][0] = aW; red[wv][1] = aWB; red[wv][2] = aI; red[wv][3] = aU; }
  __syncthreads();
  if (tid < 4)
    part[(img * NGRP + grp) * 4 + tid] =
        red[0][tid] + red[1][tid] + red[2][tid] + red[3][tid];
}

// ---- finalize: reduce 1024 block-partials -> scalar loss ----
__global__ void sloss_final(const float* __restrict__ part,
                            float* __restrict__ out) {
  __shared__ float s[128];
  int tid = threadIdx.x;          // 128 threads
  int img = tid >> 2, q = tid & 3;
  float v = 0.f;
#pragma unroll 4
  for (int g = 0; g < NGRP; ++g) v += part[((img << 5) + g) * 4 + q];
  s[tid] = v;
  __syncthreads();
  float loss = 0.f;
  if (tid < NB) {
    float aW  = s[tid * 4 + 0];
    float aWB = s[tid * 4 + 1];
    float aI  = s[tid * 4 + 2];
    float aU  = s[tid * 4 + 3];
    loss = aWB / aW + 1.0f - (aI + 1.0f) / (aU - aI + 1.0f);
  }
  loss = wave_reduce(loss);
  if (tid == 0) out[0] = loss * (1.0f / (float)NB);
}

extern "C" void kernel_launch(void* const* d_in, const int* in_sizes, int n_in,
                              void* d_out, int out_size, void* d_ws, size_t ws_size,
                              hipStream_t stream) {
  const float* x = (const float*)d_in[0];
  const float* t = (const float*)d_in[1];
  float* part = (float*)d_ws;     // 1024 x 4 floats, fully overwritten

  sloss_main<<<NB * NGRP, NTH, 0, stream>>>(x, t, part);
  sloss_final<<<1, 128, 0, stream>>>(part, (float*)d_out);
}

// Round 11
// 107.128 us; speedup vs baseline: 1.1003x; 1.0809x over previous
//
#include <hip/hip_runtime.h>
#include <math.h>

// StructureLoss — R11: single-variable isolation vs R10.
// R10 (R9b) regressed vs R7 (106.5 -> 115.8) with two simultaneous changes:
// (a) tails-from-registers, (b) nontemporal x loads. R11 removes ONLY (b).
// If total <= ~107: nt was the culprit, keep register-tails.
// If total ~115: (a) causes VGPR spills -> revert to exact R7 next.

#define IMG_H 512
#define IMG_W 512
#define NB    32
#define HW    (IMG_H * IMG_W)
#define RG    16              // output rows per block
#define NGRP  (IMG_H / RG)    // 32 row-groups per image
#define NTH   256
#define VST   576             // LDS row stride (floats); 512 + 16*4 skew

// skew +4 floats per 32-col chunk: chunk s occupies [36s, 36s+31], 16B-aligned
__device__ __forceinline__ int vidx(int c) { return c + 4 * (c >> 5); }

__device__ __forceinline__ float wave_reduce(float v) {
#pragma unroll
  for (int off = 32; off > 0; off >>= 1) v += __shfl_down(v, off, 64);
  return v;
}

__global__ __launch_bounds__(NTH, 4) void sloss_main(const float* __restrict__ x,
                                                     const float* __restrict__ t,
                                                     float* __restrict__ part) {
  __shared__ float vls[RG * VST];   // 16*576*4 = 36864 B -> 4 blocks/CU
  __shared__ float red[4][4];

  const int tid = threadIdx.x;
  // XCD swizzle: one image's 32 groups stay on one XCD -> halo rows L2-hit.
  const int xcd = blockIdx.x & 7;
  const int k   = blockIdx.x >> 3;        // 0..127
  const int img = (xcd << 2) | (k >> 5);  // 4 images per XCD
  const int grp = k & 31;
  const int r0  = grp * RG;
  const float* tb = t + (size_t)img * HW;
  const float* xb = x + (size_t)img * HW;

  // ---- Stage 1: vertical 31-row running sums; thread owns cols 2t,2t+1 ----
  {
    const float2* tc2 = (const float2*)tb + tid;   // row stride = 256 float2
    const int li = vidx(2 * tid);
    float sx, sy;
    if (grp >= 1 && grp <= 30) {                   // interior: no row guards
      // warm-up rows r0-15..r0+14 as one 30-load batch; w[0..15] stay live
      // as the main loop's tail rows (rows r0-15..r0) -- no tail re-loads.
      float2 w[30];
#pragma unroll
      for (int j = 0; j < 30; ++j) w[j] = tc2[(r0 - 15 + j) * 256];
      float ax = 0.f, ay = 0.f, bx2 = 0.f, by2 = 0.f, cx = 0.f, cy = 0.f;
#pragma unroll
      for (int j = 0; j < 10; ++j) { ax += w[j].x; ay += w[j].y; }
#pragma unroll
      for (int j = 10; j < 20; ++j) { bx2 += w[j].x; by2 += w[j].y; }
#pragma unroll
      for (int j = 20; j < 30; ++j) { cx += w[j].x; cy += w[j].y; }
      sx = ax + bx2 + cx; sy = ay + by2 + cy;
      // main loop: 4 rows/step, 4 head loads batched; tails from w[]
#pragma unroll
      for (int c = 0; c < 4; ++c) {
        float2 hd[4];
#pragma unroll
        for (int j = 0; j < 4; ++j) hd[j] = tc2[(r0 + 4 * c + j + 15) * 256];
#pragma unroll
        for (int j = 0; j < 4; ++j) {
          const int i = 4 * c + j;
          sx += hd[j].x; sy += hd[j].y;
          vls[i * VST + li] = sx; vls[i * VST + li + 1] = sy;
          sx -= w[i].x; sy -= w[i].y;    // tail row r0-15+i, from registers
        }
      }
    } else {                                       // edge groups: guarded
      sx = 0.f; sy = 0.f;
#pragma unroll
      for (int kk = -15; kk < 15; ++kk) {
        int r = r0 + kk;
        if ((unsigned)r < IMG_H) { float2 v = tc2[r * 256]; sx += v.x; sy += v.y; }
      }
#pragma unroll
      for (int i = 0; i < RG; ++i) {
        int ra = r0 + i + 15;
        if (ra < IMG_H) { float2 v = tc2[ra * 256]; sx += v.x; sy += v.y; }
        vls[i * VST + li] = sx; vls[i * VST + li + 1] = sy;
        int rs = r0 + i - 15;
        if (rs >= 0) { float2 u = tc2[rs * 256]; sx -= u.x; sy -= u.y; }
      }
    }
  }

  // ---- hoist stage-2 x/t loads: overlap with barrier + prefix scan ----
  const int row = tid >> 4;                 // 0..15
  const int sub = tid & 15;                 // 0..15 (32-col chunk)
  const int c0  = sub * 32;
  const float* xr = xb + (size_t)(r0 + row) * IMG_W + c0;
  const float* tr = tb + (size_t)(r0 + row) * IMG_W + c0;
  float4 xg[8], tg[8];
#pragma unroll
  for (int jc = 0; jc < 8; ++jc) {
    xg[jc] = *(const float4*)(xr + 4 * jc);
    tg[jc] = *(const float4*)(tr + 4 * jc);
  }

  __syncthreads();

  // ---- Stage 2: row prefix sums + box from registers + fused elementwise ----
  const float* vr = &vls[row * VST];
  float q[32];
  {
    const float4* rb4 = (const float4*)(vr + 36 * sub);
    float run = 0.f;
#pragma unroll
    for (int kk = 0; kk < 8; ++kk) {
      float4 vv = rb4[kk];
      q[4 * kk + 0] = run + vv.x;
      q[4 * kk + 1] = q[4 * kk + 0] + vv.y;
      q[4 * kk + 2] = q[4 * kk + 1] + vv.z;
      q[4 * kk + 3] = q[4 * kk + 2] + vv.w;
      run = q[4 * kk + 3];
    }
  }
  // segmented (width-16) inclusive scan of chunk totals across the row
  {
    float tot = q[31];
    float s = tot;
#pragma unroll
    for (int d = 1; d < 16; d <<= 1) {
      float u = __shfl_up(s, d, 64);
      if (sub >= d) s += u;
    }
    float base = s - tot;
#pragma unroll
    for (int j = 0; j < 32; ++j) q[j] += base;   // q[j] = P[c0+j]
  }

  // box[c] = P[min(c+15,511)] - (c>=16 ? P[c-16] : 0); neighbors via shfl.
  const float inv_area = 1.0f / 961.0f;
  float aW = 0.f, aWB = 0.f, aI = 0.f, aU = 0.f;
#pragma unroll
  for (int jc = 0; jc < 8; ++jc) {
    float xa[4] = {xg[jc].x, xg[jc].y, xg[jc].z, xg[jc].w};
    float ta[4] = {tg[jc].x, tg[jc].y, tg[jc].z, tg[jc].w};
#pragma unroll
    for (int e = 0; e < 4; ++e) {
      const int j = 4 * jc + e;
      float hi, lo;
      if (j <= 16) {
        hi = q[j + 15];
      } else {
        float g = __shfl_down(q[j - 17], 1);
        hi = (sub == 15) ? q[31] : g;
      }
      if (j >= 16) {
        lo = q[j - 16];
      } else {
        float g = __shfl_up(q[j + 16], 1);
        lo = (sub == 0) ? 0.f : g;
      }
      float box = hi - lo;
      float tv = ta[e], xv = xa[e];
      float w   = fmaf(5.0f, fabsf(box * inv_area - tv), 1.0f);
      float ez  = __expf(-fabsf(xv));            // single exp
      float inv = 1.0f / (1.0f + ez);
      float p   = (xv >= 0.f) ? inv : ez * inv;  // sigmoid(x)
      float bce = fmaxf(xv, 0.f) - xv * tv + __logf(1.0f + ez);
      aW  += w;
      aWB = fmaf(w, bce, aWB);
      aI  = fmaf(p * tv, w, aI);
      aU  = fmaf(p + tv, w, aU);
    }
  }

  aW  = wave_reduce(aW);
  aWB = wave_reduce(aWB);
  aI  = wave_reduce(aI);
  aU  = wave_reduce(aU);
  const int wv = tid >> 6, ln = tid & 63;
  if (ln == 0) { red[wv][0] = aW; red[wv][1] = aWB; red[wv][2] = aI; red[wv][3] = aU; }
  __syncthreads();
  if (tid < 4)
    part[(img * NGRP + grp) * 4 + tid] =
        red[0][tid] + red[1][tid] + red[2][tid] + red[3][tid];
}

// ---- finalize: reduce 1024 block-partials -> scalar loss ----
__global__ void sloss_final(const float* __restrict__ part,
                            float* __restrict__ out) {
  __shared__ float s[128];
  int tid = threadIdx.x;          // 128 threads
  int img = tid >> 2, q = tid & 3;
  float v = 0.f;
#pragma unroll 4
  for (int g = 0; g < NGRP; ++g) v += part[((img << 5) + g) * 4 + q];
  s[tid] = v;
  __syncthreads();
  float loss = 0.f;
  if (tid < NB) {
    float aW  = s[tid * 4 + 0];
    float aWB = s[tid * 4 + 1];
    float aI  = s[tid * 4 + 2];
    float aU  = s[tid * 4 + 3];
    loss = aWB / aW + 1.0f - (aI + 1.0f) / (aU - aI + 1.0f);
  }
  loss = wave_reduce(loss);
  if (tid == 0) out[0] = loss * (1.0f / (float)NB);
}

extern "C" void kernel_launch(void* const* d_in, const int* in_sizes, int n_in,
                              void* d_out, int out_size, void* d_ws, size_t ws_size,
                              hipStream_t stream) {
  const float* x = (const float*)d_in[0];
  const float* t = (const float*)d_in[1];
  float* part = (float*)d_ws;     // 1024 x 4 floats, fully overwritten

  sloss_main<<<NB * NGRP, NTH, 0, stream>>>(x, t, part);
  sloss_final<<<1, 128, 0, stream>>>(part, (float*)d_out);
}